// Round 2
// baseline (157.933 us; speedup 1.0000x reference)
//
#include <hip/hip_runtime.h>

// D_MODEL=512, H=8, B=4, S=2048.
// masked_fill(-1e9) happens BEFORE abs(), so softmax(abs(scores)) is exactly
// uniform over {k : mask[b,k]==0}, independent of query/head. Whole layer
// collapses to:
//   m[b]   = mean over masked rows of value[b]          (branchless weighted sum)
//   y[b]   = m[b] @ Wv.T + bv
//   z[b]   = y[b] @ Wo.T + bo
//   out[b,s,:] = z[b]  for all s
// Q/K/Wq/bq/Wk/bk are dead inputs.

#define DM  512
#define SEQ 2048
#define NB  4
#define CH  64            // s-chunks per batch
#define RPB (SEQ / CH)    // 32 rows per block

// ---------------------------------------------------------------------------
// Kernel A: branchless per-chunk weighted row-sum of value.
// grid = NB*CH = 256 blocks, 256 threads. Threads split into 2 row-groups of
// 128; each thread owns one float4 column slice, iterates 16 rows with
// UNCONDITIONAL loads (weight 0/1) so everything pipelines. No atomics, no
// memset: every partial slot is fully written.
// ---------------------------------------------------------------------------
__global__ void masked_partial_kernel(const float* __restrict__ value,
                                      const int* __restrict__ mask,
                                      float* __restrict__ partial,  // [NB*CH][DM]
                                      int* __restrict__ cnt_part) { // [NB*CH]
    int b  = blockIdx.x / CH;
    int ch = blockIdx.x % CH;
    int g  = threadIdx.x >> 7;    // row parity group: 0 or 1
    int c4 = threadIdx.x & 127;   // float4 column (128 per row)
    const float4* vb = (const float4*)(value + (size_t)b * SEQ * DM);
    const int*    mb = mask + b * SEQ;
    int sbeg = ch * RPB;

    float4 acc = make_float4(0.f, 0.f, 0.f, 0.f);
    int myc = 0;
#pragma unroll
    for (int it = 0; it < RPB / 2; ++it) {     // 16 iterations
        int s = sbeg + 2 * it + g;
        float w = (mb[s] == 0) ? 1.0f : 0.0f;  // branchless weight
        float4 v = vb[(size_t)s * (DM / 4) + c4];
        acc.x += w * v.x; acc.y += w * v.y; acc.z += w * v.z; acc.w += w * v.w;
        myc += (w != 0.0f);
    }

    __shared__ float4 sh[128];
    __shared__ int shc[2];
    if (g == 1) sh[c4] = acc;
    if ((threadIdx.x & 127) == 0) shc[g] = myc;
    __syncthreads();
    if (g == 0) {
        float4 o = sh[c4];
        o.x += acc.x; o.y += acc.y; o.z += acc.z; o.w += acc.w;
        ((float4*)partial)[(size_t)(b * CH + ch) * (DM / 4) + c4] = o;
    }
    if (threadIdx.x == 0) cnt_part[b * CH + ch] = shc[0] + shc[1];
}

// ---------------------------------------------------------------------------
// Kernel B: y[b][d] = scale * sum_i x_red[b][i] * W[d][i] + bias[d]
// where x_red is the chunk-reduction of x (nchunks partial rows) and
// scale = 1/count (matvec1) or 1 (matvec2).
// grid = (8, NB), 256 threads = 4 waves; each wave handles 16 output dims
// with float4 W-row loads + 64-lane shuffle reduction.
// ---------------------------------------------------------------------------
__global__ void matvec_kernel(const float* __restrict__ x,      // [NB*nchunks][DM]
                              const int* __restrict__ cnt_part, // [NB*nchunks] or null
                              const float* __restrict__ W,      // [DM][DM] row-major
                              const float* __restrict__ bias,
                              float* __restrict__ y,            // [NB][DM]
                              int nchunks, int use_cnt) {
    __shared__ alignas(16) float xsf[DM];
    __shared__ float sscale;
    int b = blockIdx.y;

    if (use_cnt) {
        if (threadIdx.x < 64) {
            int csum = 0;
            for (int c = threadIdx.x; c < nchunks; c += 64)
                csum += cnt_part[b * nchunks + c];
#pragma unroll
            for (int off = 32; off; off >>= 1) csum += __shfl_down(csum, off);
            if (threadIdx.x == 0) sscale = 1.0f / (float)(csum < 1 ? 1 : csum);
        }
    } else if (threadIdx.x == 0) {
        sscale = 1.0f;
    }

    for (int i = threadIdx.x; i < DM; i += 256) {
        float s = 0.f;
        for (int c = 0; c < nchunks; ++c)
            s += x[((size_t)b * nchunks + c) * DM + i];
        xsf[i] = s;
    }
    __syncthreads();
    float scale = sscale;

    int lane = threadIdx.x & 63;
    int wave = threadIdx.x >> 6;
    const float4* xs4 = (const float4*)xsf;
    float4 x0 = xs4[lane];
    float4 x1 = xs4[64 + lane];

    for (int j = wave; j < 64; j += 4) {
        int d = blockIdx.x * 64 + j;
        const float4* w4 = (const float4*)(W + (size_t)d * DM);
        float4 a = w4[lane];
        float4 c = w4[64 + lane];
        float sum = a.x * x0.x + a.y * x0.y + a.z * x0.z + a.w * x0.w
                  + c.x * x1.x + c.y * x1.y + c.z * x1.z + c.w * x1.w;
#pragma unroll
        for (int off = 32; off; off >>= 1) sum += __shfl_down(sum, off);
        if (lane == 0) y[b * DM + d] = sum * scale + bias[d];
    }
}

// ---------------------------------------------------------------------------
// Kernel C: broadcast z[b][512] to out[b][s][512]. Pure float4 store BW.
// ---------------------------------------------------------------------------
__global__ void broadcast_kernel(const float* __restrict__ z,
                                 float4* __restrict__ out) {
    const int TOT4 = NB * SEQ * DM / 4;  // 2^20
    const float4* z4 = (const float4*)z;
    int idx = blockIdx.x * blockDim.x + threadIdx.x;
    int stride = gridDim.x * blockDim.x;
    for (int i = idx; i < TOT4; i += stride) {
        int b  = i >> 18;   // SEQ*DM/4 float4 per batch
        int d4 = i & 127;   // DM/4 float4 per row
        out[i] = z4[b * 128 + d4];
    }
}

extern "C" void kernel_launch(void* const* d_in, const int* in_sizes, int n_in,
                              void* d_out, int out_size, void* d_ws, size_t ws_size,
                              hipStream_t stream) {
    // Input order: query,key,value,mask,Wq,bq,Wk,bk,Wv,bv,Wo,bo
    const float* value = (const float*)d_in[2];
    const int*   mask  = (const int*)d_in[3];
    const float* Wv    = (const float*)d_in[8];
    const float* bv    = (const float*)d_in[9];
    const float* Wo    = (const float*)d_in[10];
    const float* bo    = (const float*)d_in[11];
    float* out = (float*)d_out;

    // Workspace: partial[NB*CH*DM] | cnt_part[NB*CH] | y[NB*DM] | z[NB*DM]
    float* partial  = (float*)d_ws;
    int*   cnt_part = (int*)(partial + NB * CH * DM);
    float* y        = (float*)(cnt_part + NB * CH);
    float* z        = y + NB * DM;

    masked_partial_kernel<<<dim3(NB * CH), dim3(256), 0, stream>>>(value, mask, partial, cnt_part);
    matvec_kernel<<<dim3(8, NB), dim3(256), 0, stream>>>(partial, cnt_part, Wv, bv, y, CH, 1);
    matvec_kernel<<<dim3(8, NB), dim3(256), 0, stream>>>(y, nullptr, Wo, bo, z, 1, 0);
    broadcast_kernel<<<dim3(2048), dim3(256), 0, stream>>>(z, (float4*)out);
}

// Round 3
// 126.480 us; speedup vs baseline: 1.2487x; 1.2487x over previous
//
#include <hip/hip_runtime.h>

// D_MODEL=512, H=8, B=4, S=2048.
// masked_fill(-1e9) happens BEFORE abs(), so softmax(abs(scores)) is exactly
// uniform over {k : mask[b,k]==0}, independent of query/head. Whole layer
// collapses to:
//   m[b]   = mean over masked rows of value[b]
//   y[b]   = m[b] @ Wv.T + bv
//   z[b]   = y[b] @ Wo.T + bo
//   out[b,s,:] = z[b]  for all s
// Q/K/Wq/bq/Wk/bk are dead inputs.
//
// R3 changes (latency pipelining):
//  - matvec1 chunk-reduce loop now compile-time CH=64 + #pragma unroll
//    (R2's runtime-bound loop serialized 128 x ~700cyc loads = 37us).
//  - j-loops rewritten with static trip count 16 + unroll so W-row loads
//    and shuffle chains interleave.
//  - matvec2 fused with broadcast: 256 blocks each compute a redundant
//    64-dim z-slice and write a 64col x 256row output tile (write BW needs
//    ~256 blocks; 32-block broadcast would be per-CU BW-limited).

#define DM  512
#define SEQ 2048
#define NB  4
#define CH  64            // s-chunks per batch for kernel A
#define RPB (SEQ / CH)    // 32 rows per chunk

// ---------------------------------------------------------------------------
// Kernel A: branchless per-chunk weighted row-sum of value + count.
// grid = NB*CH = 256 blocks, 256 threads.
// ---------------------------------------------------------------------------
__global__ void masked_partial_kernel(const float* __restrict__ value,
                                      const int* __restrict__ mask,
                                      float* __restrict__ partial,  // [NB*CH][DM]
                                      int* __restrict__ cnt_part) { // [NB*CH]
    int b  = blockIdx.x / CH;
    int ch = blockIdx.x % CH;
    int g  = threadIdx.x >> 7;    // row parity group: 0 or 1
    int c4 = threadIdx.x & 127;   // float4 column (128 per row)
    const float4* vb = (const float4*)(value + (size_t)b * SEQ * DM);
    const int*    mb = mask + b * SEQ;
    int sbeg = ch * RPB;

    float4 acc = make_float4(0.f, 0.f, 0.f, 0.f);
    int myc = 0;
#pragma unroll
    for (int it = 0; it < RPB / 2; ++it) {     // 16 iterations, all independent
        int s = sbeg + 2 * it + g;
        float w = (mb[s] == 0) ? 1.0f : 0.0f;  // branchless weight
        float4 v = vb[(size_t)s * (DM / 4) + c4];
        acc.x += w * v.x; acc.y += w * v.y; acc.z += w * v.z; acc.w += w * v.w;
        myc += (w != 0.0f);
    }

    __shared__ float4 sh[128];
    __shared__ int shc[2];
    if (g == 1) sh[c4] = acc;
    if ((threadIdx.x & 127) == 0) shc[g] = myc;
    __syncthreads();
    if (g == 0) {
        float4 o = sh[c4];
        o.x += acc.x; o.y += acc.y; o.z += acc.z; o.w += acc.w;
        ((float4*)partial)[(size_t)(b * CH + ch) * (DM / 4) + c4] = o;
    }
    if (threadIdx.x == 0) cnt_part[b * CH + ch] = shc[0] + shc[1];
}

// ---------------------------------------------------------------------------
// Kernel B: y[b][d] = (1/cnt[b]) * sum_i xsum[b][i] * Wv[d][i] + bv[d]
// where xsum is the fully-unrolled reduction of the CH=64 partial rows.
// grid = (8, NB), 256 threads = 4 waves; wave handles 16 output dims.
// ---------------------------------------------------------------------------
__global__ void matvec1_kernel(const float* __restrict__ partial,  // [NB*CH][DM]
                               const int* __restrict__ cnt_part,   // [NB*CH]
                               const float* __restrict__ W,        // [DM][DM]
                               const float* __restrict__ bias,
                               float* __restrict__ y) {            // [NB][DM]
    __shared__ alignas(16) float xsf[DM];
    __shared__ float sscale;
    int b = blockIdx.y;
    int t = threadIdx.x;

    if (t < 64) {  // wave 0: count reduction
        int csum = cnt_part[b * CH + t];
#pragma unroll
        for (int off = 32; off; off >>= 1) csum += __shfl_down(csum, off);
        if (t == 0) sscale = 1.0f / (float)(csum < 1 ? 1 : csum);
    }

    // Chunk reduction: compile-time trip count -> fully pipelined loads.
    {
        const float* pb = partial + (size_t)b * CH * DM;
        float s0 = 0.f, s1 = 0.f;
#pragma unroll
        for (int c = 0; c < CH; ++c) {
            s0 += pb[(size_t)c * DM + t];
            s1 += pb[(size_t)c * DM + t + 256];
        }
        xsf[t] = s0;
        xsf[t + 256] = s1;
    }
    __syncthreads();
    float scale = sscale;

    int lane = t & 63;
    int wave = t >> 6;
    const float4* xs4 = (const float4*)xsf;
    float4 x0 = xs4[lane];
    float4 x1 = xs4[64 + lane];

#pragma unroll
    for (int jj = 0; jj < 16; ++jj) {
        int j = jj * 4 + wave;
        int d = blockIdx.x * 64 + j;
        const float4* w4 = (const float4*)(W + (size_t)d * DM);
        float4 a = w4[lane];
        float4 c = w4[64 + lane];
        float sum = a.x * x0.x + a.y * x0.y + a.z * x0.z + a.w * x0.w
                  + c.x * x1.x + c.y * x1.y + c.z * x1.z + c.w * x1.w;
#pragma unroll
        for (int off = 32; off; off >>= 1) sum += __shfl_down(sum, off);
        if (lane == 0) y[b * DM + d] = sum * scale + bias[d];
    }
}

// ---------------------------------------------------------------------------
// Kernel C: fused matvec2 + broadcast.
// grid = (8 col-slices, 8 s-slices, NB), 256 threads.
// Each block computes z[b][bx*64 .. bx*64+64] (redundantly across the 8
// s-slices; Wo slice is L2-resident) then writes its 64col x 256row tile.
// ---------------------------------------------------------------------------
__global__ void matvec2_bcast_kernel(const float* __restrict__ y,    // [NB][DM]
                                     const float* __restrict__ W,    // [DM][DM]
                                     const float* __restrict__ bias,
                                     float4* __restrict__ out) {
    __shared__ alignas(16) float ysf[DM];
    __shared__ alignas(16) float zloc[64];
    int bx = blockIdx.x;   // 0..7 column slice
    int sy = blockIdx.y;   // 0..7 sequence slice
    int b  = blockIdx.z;   // 0..3
    int t  = threadIdx.x;

    ysf[t]       = y[b * DM + t];
    ysf[t + 256] = y[b * DM + t + 256];
    __syncthreads();

    int lane = t & 63;
    int wave = t >> 6;
    const float4* ys4 = (const float4*)ysf;
    float4 x0 = ys4[lane];
    float4 x1 = ys4[64 + lane];

#pragma unroll
    for (int jj = 0; jj < 16; ++jj) {
        int j = jj * 4 + wave;
        int d = bx * 64 + j;
        const float4* w4 = (const float4*)(W + (size_t)d * DM);
        float4 a = w4[lane];
        float c4x = a.x * x0.x + a.y * x0.y + a.z * x0.z + a.w * x0.w;
        float4 c = w4[64 + lane];
        float sum = c4x
                  + c.x * x1.x + c.y * x1.y + c.z * x1.z + c.w * x1.w;
#pragma unroll
        for (int off = 32; off; off >>= 1) sum += __shfl_down(sum, off);
        if (lane == 0) zloc[j] = sum + bias[d];
    }
    __syncthreads();

    // Write tile: rows [sy*256, sy*256+256), float4-cols [bx*16, bx*16+16).
    int j4   = t & 15;         // float4 column within slice
    int srow = t >> 4;         // 0..15: row offset within a 16-row pass
    float4 zreg = ((const float4*)zloc)[j4];
#pragma unroll
    for (int ss = 0; ss < 16; ++ss) {
        int s = sy * 256 + ss * 16 + srow;
        out[(size_t)(b * SEQ + s) * (DM / 4) + bx * 16 + j4] = zreg;
    }
}

extern "C" void kernel_launch(void* const* d_in, const int* in_sizes, int n_in,
                              void* d_out, int out_size, void* d_ws, size_t ws_size,
                              hipStream_t stream) {
    // Input order: query,key,value,mask,Wq,bq,Wk,bk,Wv,bv,Wo,bo
    const float* value = (const float*)d_in[2];
    const int*   mask  = (const int*)d_in[3];
    const float* Wv    = (const float*)d_in[8];
    const float* bv    = (const float*)d_in[9];
    const float* Wo    = (const float*)d_in[10];
    const float* bo    = (const float*)d_in[11];
    float* out = (float*)d_out;

    // Workspace: partial[NB*CH*DM] | cnt_part[NB*CH] | y[NB*DM]
    float* partial  = (float*)d_ws;
    int*   cnt_part = (int*)(partial + NB * CH * DM);
    float* y        = (float*)(cnt_part + NB * CH);

    masked_partial_kernel<<<dim3(NB * CH), dim3(256), 0, stream>>>(value, mask, partial, cnt_part);
    matvec1_kernel<<<dim3(8, NB), dim3(256), 0, stream>>>(partial, cnt_part, Wv, bv, y);
    matvec2_bcast_kernel<<<dim3(8, 8, NB), dim3(256), 0, stream>>>(y, Wo, bo, (float4*)out);
}